// Round 1
// baseline (1255.826 us; speedup 1.0000x reference)
//
#include <hip/hip_runtime.h>
#include <stdint.h>

#define NPIX 1024
#define NEDGE 1984
#define NSORT 2048
#define CHUNK 16
#define CNTW (NPIX + 2)   // pad rows: stride 2052B -> replay lanes hit distinct banks

struct SMem {
  union {
    unsigned long long keys[NSORT];   // 16384 B  (sort + phase1)
    uint16_t cnt[CHUNK][CNTW];        // 32832 B  (phase2 replay)
  } u;
  float    Pw[NPIX];          // window y_pred
  uint16_t lab[NPIX];         // CC labels (min pixel id + 1), 0 = unlabeled
  uint16_t par[NPIX];         // union-find parent
  uint16_t tot[NPIX];         // labeled-node count per root
  uint16_t labDense[NPIX];    // dense label id, stored at component-min pixel
  uint16_t recE[NPIX];        // merge records (<=1023 used)
  uint16_t recA[NPIX];
  uint16_t recB[NPIX];
  uint32_t totprod[NPIX];     // totA*totB at merge time
  uint32_t same[NPIX];        // same-label pairs at merge (filled by replay)
  uint8_t  maskv[NPIX];       // T==0 (background / labeled)
  uint8_t  gtclass[NEDGE];    // # endpoints with T!=0 : 0,1,2
  double   red[256];
  unsigned int minPb, maxPb, minTb, maxTb, Ssum;
  int nlabs, Msh, changed;
};

__device__ __forceinline__ void edge_nodes(int e, int& a, int& b) {
  if (e < 992) { int r = e / 31; int c = e - r * 31; a = (r << 5) + c; b = a + 1; }
  else         { a = e - 992; b = a + 32; }
}

__global__ __launch_bounds__(256) void malis_kernel(
    const float* __restrict__ y_true, const float* __restrict__ y_pred,
    double* __restrict__ part_out)
{
  __shared__ SMem s;
  const int tid  = threadIdx.x;
  const int bid  = blockIdx.x;
  const int sign = bid & 1;          // 0 = neg, 1 = pos
  const int win  = (bid >> 1) & 63;
  const int bat  = bid >> 7;
  const int wr = win >> 3, wc = win & 7;

  if (tid == 0) {
    s.minPb = 0xFFFFFFFFu; s.maxPb = 0u; s.minTb = 0xFFFFFFFFu; s.maxTb = 0u;
    s.nlabs = 0; s.Msh = 0; s.Ssum = 0u;
  }
  __syncthreads();

  // ---- load window; min/max over BOTH batches for the exact skip predicate
  for (int i = tid; i < 2 * NPIX; i += 256) {
    int bb = i >> 10, p = i & (NPIX - 1);
    int r = p >> 5, c = p & 31;
    size_t g = ((size_t)(bb * 256 + wr * 32 + r)) * 256 + (size_t)(wc * 32 + c);
    float pv = y_pred[g], tv = y_true[g];
    atomicMin(&s.minPb, __float_as_uint(pv));   // valid: all values >= 0
    atomicMax(&s.maxPb, __float_as_uint(pv));
    atomicMin(&s.minTb, __float_as_uint(tv));
    atomicMax(&s.maxTb, __float_as_uint(tv));
    if (bb == bat) { s.Pw[p] = pv; s.maskv[p] = (tv == 0.0f) ? 1 : 0; }
  }
  __syncthreads();

  {
    float mnP = __uint_as_float(s.minPb), mxP = __uint_as_float(s.maxPb);
    float mnT = __uint_as_float(s.minTb), mxT = __uint_as_float(s.maxTb);
    if (mnP == 1.0f || mxP == 0.0f || mnT == 1.0f || mxT == 0.0f) {
      if (tid == 0) part_out[bid] = 0.0;
      return;                                   // uniform across block
    }
  }

  // ---- edge keys (cost desc, index asc  ->  pack (~bits(cost), e), sort asc)
  for (int e = tid; e < NSORT; e += 256) {
    if (e < NEDGE) {
      int a, b; edge_nodes(e, a, b);
      int cls = (s.maskv[a] ? 0 : 1) + (s.maskv[b] ? 0 : 1);
      s.gtclass[e] = (uint8_t)cls;
      float cost = s.Pw[a] + s.Pw[b];
      if (sign == 0) { if (cls == 2) cost = 20.0f; }   // costs_n[gt>20]=20
      else           { if (cls == 0) cost = 0.0f;  }   // costs_p[gt<10]=0
      s.u.keys[e] = (((unsigned long long)(__float_as_uint(cost) ^ 0xFFFFFFFFu)) << 32)
                    | (unsigned long long)(unsigned)e;
    } else {
      s.u.keys[e] = ~0ull;                             // pad sorts to end
    }
  }
  for (int p = tid; p < NPIX; p += 256) {
    s.lab[p] = s.maskv[p] ? (uint16_t)(p + 1) : (uint16_t)0;
    s.par[p] = (uint16_t)p;
    s.tot[p] = (uint16_t)s.maskv[p];
    s.same[p] = 0u;
    s.totprod[p] = 0u;
  }
  __syncthreads();

  // ---- 8-connected components of maskv: monotone min-propagation + jumps
  for (;;) {
    if (tid == 0) s.changed = 0;
    __syncthreads();
    for (int p = tid; p < NPIX; p += 256) {
      if (!s.maskv[p]) continue;
      int r = p >> 5, c = p & 31;
      unsigned m = s.lab[p];
      bool up = r > 0, dn = r < 31, lf = c > 0, rt = c < 31;
      if (up) {
        if (s.maskv[p-32])       { unsigned v = s.lab[p-32]; if (v < m) m = v; }
        if (lf && s.maskv[p-33]) { unsigned v = s.lab[p-33]; if (v < m) m = v; }
        if (rt && s.maskv[p-31]) { unsigned v = s.lab[p-31]; if (v < m) m = v; }
      }
      if (dn) {
        if (s.maskv[p+32])       { unsigned v = s.lab[p+32]; if (v < m) m = v; }
        if (lf && s.maskv[p+31]) { unsigned v = s.lab[p+31]; if (v < m) m = v; }
        if (rt && s.maskv[p+33]) { unsigned v = s.lab[p+33]; if (v < m) m = v; }
      }
      if (lf && s.maskv[p-1]) { unsigned v = s.lab[p-1]; if (v < m) m = v; }
      if (rt && s.maskv[p+1]) { unsigned v = s.lab[p+1]; if (v < m) m = v; }
      unsigned m2 = s.lab[m - 1]; if (m2 && m2 < m) m = m2;   // pointer jump
      m2 = s.lab[m - 1];          if (m2 && m2 < m) m = m2;   // jump again
      if (m < (unsigned)s.lab[p]) { s.lab[p] = (uint16_t)m; s.changed = 1; }
    }
    __syncthreads();
    int ch = s.changed;
    __syncthreads();
    if (!ch) break;
  }

  // ---- compact labels to dense ids (assignment order irrelevant: sums exact)
  for (int p = tid; p < NPIX; p += 256)
    if (s.maskv[p] && s.lab[p] == (uint16_t)(p + 1))
      s.labDense[p] = (uint16_t)atomicAdd(&s.nlabs, 1);
  __syncthreads();

  // ---- bitonic sort (ascending) of 2048 keys, 256 threads
  for (int k = 2; k <= NSORT; k <<= 1) {
    for (int j = k >> 1; j > 0; j >>= 1) {
      __syncthreads();
      for (int i = tid; i < NSORT; i += 256) {
        int ixj = i ^ j;
        if (ixj > i) {
          unsigned long long A = s.u.keys[i], B = s.u.keys[ixj];
          bool asc = ((i & k) == 0);
          if ((A > B) == asc) { s.u.keys[i] = B; s.u.keys[ixj] = A; }
        }
      }
    }
  }
  __syncthreads();

  // ---- phase 1: serial Kruskal (thread 0), record merge sequence
  if (tid == 0) {
    int m = 0;
    for (int sidx = 0; sidx < NSORT; ++sidx) {
      unsigned e = (unsigned)(s.u.keys[sidx]);   // low 32 bits = edge index
      if (e >= (unsigned)NEDGE) continue;
      int a, b; edge_nodes((int)e, a, b);
      int x = a, px = s.par[x];
      while (px != x) { int gp = s.par[px]; s.par[x] = (uint16_t)gp; x = gp; px = s.par[x]; }
      int ra = x;
      x = b; px = s.par[x];
      while (px != x) { int gp = s.par[px]; s.par[x] = (uint16_t)gp; x = gp; px = s.par[x]; }
      int rb = x;
      if (ra == rb) continue;
      unsigned ta = s.tot[ra], tb = s.tot[rb];
      if (tb > 0u) {                    // records with tb==0 are replay no-ops
        s.recE[m] = (uint16_t)e; s.recA[m] = (uint16_t)ra; s.recB[m] = (uint16_t)rb;
        s.totprod[m] = ta * tb;
        ++m;
      }
      s.par[rb] = (uint16_t)ra;         // same orientation as reference
      s.tot[ra] = (uint16_t)(ta + tb);
    }
    s.Msh = m;
  }
  __syncthreads();

  const int M = s.Msh;
  const int nlab = s.nlabs;

  // ---- phase 2: replay merge list per label (CHUNK labels at a time)
  for (int chb = 0; chb < nlab; chb += CHUNK) {
    for (int i = tid; i < (CHUNK * CNTW) / 2; i += 256) ((uint32_t*)s.u.cnt)[i] = 0u;
    __syncthreads();
    for (int p = tid; p < NPIX; p += 256) {
      if (s.maskv[p]) {
        int dl = (int)s.labDense[s.lab[p] - 1] - chb;
        if (dl >= 0 && dl < CHUNK) s.u.cnt[dl][p] = 1;
      }
    }
    __syncthreads();
    if (tid < CHUNK) {
      for (int m = 0; m < M; ++m) {
        int rb = s.recB[m];
        unsigned cb = s.u.cnt[tid][rb];
        if (cb) {
          int ra = s.recA[m];
          unsigned ca = s.u.cnt[tid][ra];
          if (ca) atomicAdd(&s.same[m], ca * cb);   // integer, order-independent
          s.u.cnt[tid][ra] = (uint16_t)(ca + cb);
        }
      }
    }
    __syncthreads();
  }

  // ---- normalization sum S (over ALL edges, pre-mask) and masked contribution
  unsigned mys = 0u;
  for (int m = tid; m < M; m += 256)
    mys += sign ? s.same[m] : (s.totprod[m] - s.same[m]);
  atomicAdd(&s.Ssum, mys);
  __syncthreads();
  const unsigned S = s.Ssum;

  double part = 0.0;
  if (S > 0u) {
    for (int m = tid; m < M; m += 256) {
      unsigned np = sign ? s.same[m] : (s.totprod[m] - s.same[m]);
      if (np == 0u) continue;
      int e = s.recE[m];
      int cls = s.gtclass[e];
      bool keep = sign ? (cls != 0)    // ewp[gt<20]=0  -> keep cls 1,2
                       : (cls == 0);   // ewn[gt>=10]=0 -> keep cls 0
      if (!keep) continue;
      int a, b; edge_nodes(e, a, b);
      double fa, fb;
      if (sign) {
        double da = 20.0 - (double)s.Pw[a], db = 20.0 - (double)s.Pw[b];
        fa = da * da; fb = db * db;
      } else {
        fa = (double)s.Pw[a] * (double)s.Pw[a];
        fb = (double)s.Pw[b] * (double)s.Pw[b];
      }
      part += (double)np * (fa + fb);
    }
  }
  s.red[tid] = part;
  __syncthreads();
  for (int st = 128; st > 0; st >>= 1) {
    if (tid < st) s.red[tid] += s.red[tid + st];
    __syncthreads();
  }
  if (tid == 0) part_out[bid] = (S > 0u) ? (s.red[0] / (double)S) : 0.0;
}

__global__ __launch_bounds__(256) void final_reduce(
    const double* __restrict__ part, float* __restrict__ out)
{
  __shared__ double r[256];
  int t = threadIdx.x;
  r[t] = part[t];
  __syncthreads();
  for (int st = 128; st > 0; st >>= 1) {
    if (t < st) r[t] += r[t + st];
    __syncthreads();
  }
  if (t == 0) out[0] = (float)r[0];
}

extern "C" void kernel_launch(void* const* d_in, const int* in_sizes, int n_in,
                              void* d_out, int out_size, void* d_ws, size_t ws_size,
                              hipStream_t stream) {
  const float* y_true = (const float*)d_in[0];
  const float* y_pred = (const float*)d_in[1];
  double* wsd = (double*)d_ws;            // 256 doubles of scratch
  malis_kernel<<<256, 256, 0, stream>>>(y_true, y_pred, wsd);
  final_reduce<<<1, 256, 0, stream>>>(wsd, (float*)d_out);
}